// Round 2
// baseline (85.283 us; speedup 1.0000x reference)
//
#include <hip/hip_runtime.h>

// MaxRecallLoss: single fused kernel, last-block-done final reduction.
// B = 2,097,152 samples, C = 8 classes. Cancer classes {0,1,3} -> mask 0xB.
//
// d_ws layout (floats): [0,NB) ce partials | [NB,2NB) tp | [2NB,3NB) cnt
//                       then 1 uint counter at float-offset 3*NB.

constexpr int C  = 8;
constexpr int NT = 256;   // threads per block
constexpr int NB = 2048;  // blocks (8 per CU), grid-stride over B

__device__ __forceinline__ float wave_reduce_sum(float v) {
    #pragma unroll
    for (int off = 32; off > 0; off >>= 1) v += __shfl_down(v, off, 64);
    return v;
}

__global__ __launch_bounds__(NT) void mrl_fused(
    const float* __restrict__ logits,
    const int*   __restrict__ targets,
    const float* __restrict__ counts,
    float*       __restrict__ part,     // [3*NB]
    unsigned int* __restrict__ counter, // 1 uint, memset to 0 before launch
    float*       __restrict__ out,
    int B)
{
    __shared__ float s_bw[C];
    __shared__ float s_red[(NT / 64) * 3];
    __shared__ int   s_last;

    if (threadIdx.x == 0) {
        float w[C];
        float ws = 0.0f;
        #pragma unroll
        for (int c = 0; c < C; ++c) { w[c] = rsqrtf(counts[c] + 1.0f); ws += w[c]; }
        const float scale = (float)C / ws;
        #pragma unroll
        for (int c = 0; c < C; ++c) s_bw[c] = w[c] * scale;
    }
    __syncthreads();

    const float inv_temp = 1.0f / 1.5f;
    const float c_uni   = 0.05f / 8.0f;
    const float c_one   = 1.0f - 0.05f;
    const float b_uni   = 0.1f / 8.0f;
    const float b_one   = 1.0f - 0.1f;
    const float b_extra = 0.1f * 0.5f / 3.0f;
    const float b_norm  = 1.0f / (1.0f + 3.0f * (0.1f * 0.5f / 3.0f)); // 1/1.05

    float ce_sum = 0.0f, tp_sum = 0.0f, cnt_sum = 0.0f;

    const int stride = gridDim.x * blockDim.x;
    for (int i = blockIdx.x * blockDim.x + threadIdx.x; i < B; i += stride) {
        const float4* row = reinterpret_cast<const float4*>(logits + (size_t)i * 8);
        const float4 a = row[0];
        const float4 b = row[1];
        const float l[8] = {a.x, a.y, a.z, a.w, b.x, b.y, b.z, b.w};
        const int t = targets[i];

        // max + argmax (first-max tie-break, matches jnp.argmax)
        float m = l[0];
        int   p = 0;
        #pragma unroll
        for (int j = 1; j < 8; ++j) { if (l[j] > m) { m = l[j]; p = j; } }

        // temp-1 softmax pieces (cancer prob)
        float se = 0.0f, e0, e1, e3;
        {
            float e[8];
            #pragma unroll
            for (int j = 0; j < 8; ++j) { e[j] = __expf(l[j] - m); se += e[j]; }
            e0 = e[0]; e1 = e[1]; e3 = e[3];
        }
        const float cp = (e0 + e1 + e3) / se;

        // temp-1.5 log-sum-exp
        float se2 = 0.0f;
        #pragma unroll
        for (int j = 0; j < 8; ++j) se2 += __expf((l[j] - m) * inv_temp);
        const float logZ = m * inv_temp + __logf(se2);

        // dot(smoothed_labels, x) without materializing the row
        float S = 0.0f;
        #pragma unroll
        for (int j = 0; j < 8; ++j) S += l[j];
        const float X  = S * inv_temp;
        const float Xc = (l[0] + l[1] + l[3]) * inv_temp;
        float lt = l[0];
        #pragma unroll
        for (int j = 1; j < 8; ++j) lt = (t == j) ? l[j] : lt;
        const float xt = lt * inv_temp;

        const bool isct = ((1u << t) & 0xBu) != 0u;
        const bool iscp = ((1u << p) & 0xBu) != 0u;

        float dot;
        if (isct) dot = c_uni * X + c_one * xt;
        else      dot = (b_uni * X + b_one * xt + b_extra * Xc) * b_norm;

        float ce = (logZ - dot) * s_bw[t];

        float mult = (isct && !iscp) ? 3.0f : 1.0f;
        if (t == 0 && !iscp) mult = 5.0f;
        if (isct && p != t) mult *= 2.0f;
        ce *= mult;

        ce_sum += ce;
        if (isct) { tp_sum += cp; cnt_sum += 1.0f; }
    }

    // block reduction (fixed order -> deterministic)
    float v0 = wave_reduce_sum(ce_sum);
    float v1 = wave_reduce_sum(tp_sum);
    float v2 = wave_reduce_sum(cnt_sum);
    const int lane = threadIdx.x & 63;
    const int wid  = threadIdx.x >> 6;
    if (lane == 0) {
        s_red[wid * 3 + 0] = v0;
        s_red[wid * 3 + 1] = v1;
        s_red[wid * 3 + 2] = v2;
    }
    __syncthreads();
    if (threadIdx.x == 0) {
        float r0 = 0.0f, r1 = 0.0f, r2 = 0.0f;
        #pragma unroll
        for (int w = 0; w < NT / 64; ++w) {
            r0 += s_red[w * 3 + 0];
            r1 += s_red[w * 3 + 1];
            r2 += s_red[w * 3 + 2];
        }
        part[blockIdx.x]          = r0;
        part[NB + blockIdx.x]     = r1;
        part[2 * NB + blockIdx.x] = r2;
        __threadfence();  // release partials (agent scope: wbL2)
        const unsigned prev = atomicAdd(counter, 1u);  // device-scope
        s_last = (prev == (unsigned)(NB - 1)) ? 1 : 0;
    }
    __syncthreads();

    if (s_last) {
        __threadfence();  // acquire: invalidate stale L1/L2 before reading partials
        float ce = 0.0f, tp = 0.0f, cnt = 0.0f;
        for (int k = threadIdx.x; k < NB; k += NT) {
            ce  += part[k];
            tp  += part[NB + k];
            cnt += part[2 * NB + k];
        }
        float w0 = wave_reduce_sum(ce);
        float w1 = wave_reduce_sum(tp);
        float w2 = wave_reduce_sum(cnt);
        if (lane == 0) {
            s_red[wid * 3 + 0] = w0;
            s_red[wid * 3 + 1] = w1;
            s_red[wid * 3 + 2] = w2;
        }
        __syncthreads();
        if (threadIdx.x == 0) {
            float r0 = 0.0f, r1 = 0.0f, r2 = 0.0f;
            #pragma unroll
            for (int w = 0; w < NT / 64; ++w) {
                r0 += s_red[w * 3 + 0];
                r1 += s_red[w * 3 + 1];
                r2 += s_red[w * 3 + 2];
            }
            const float base_loss   = r0 / (float)B;
            const float recall_loss = 1.0f - r1 / (r2 + 1e-8f);
            out[0] = base_loss + 0.5f * recall_loss;
        }
    }
}

extern "C" void kernel_launch(void* const* d_in, const int* in_sizes, int n_in,
                              void* d_out, int out_size, void* d_ws, size_t ws_size,
                              hipStream_t stream) {
    const float* logits  = (const float*)d_in[0];
    const int*   targets = (const int*)d_in[1];
    const float* counts  = (const float*)d_in[2];
    float* out  = (float*)d_out;
    float* part = (float*)d_ws;                          // 3*NB floats
    unsigned int* counter = (unsigned int*)(part + 3 * NB);

    const int B = in_sizes[1];

    // reset the completion counter (graph-capturable memset node)
    hipMemsetAsync(counter, 0, sizeof(unsigned int), stream);
    mrl_fused<<<NB, NT, 0, stream>>>(logits, targets, counts, part, counter, out, B);
}

// Round 3
// 22.076 us; speedup vs baseline: 3.8631x; 3.8631x over previous
//
#include <hip/hip_runtime.h>

// MaxRecallLoss: fused per-sample loss (pass1) + tiny deterministic pass2.
// B = 2,097,152 samples, C = 8 classes. Cancer classes {0,1,3} -> mask 0xB.
// R2 lesson: last-block-done w/ per-block threadfence+atomic = 4x regression
// on gfx950 (2048 wbl2 + contended cross-XCD atomic). Two kernels it is.

constexpr int C  = 8;
constexpr int NT = 256;   // threads per block
constexpr int NB = 1024;  // blocks in pass 1 (4 per CU), grid-stride over B

__device__ __forceinline__ float wave_reduce_sum(float v) {
    #pragma unroll
    for (int off = 32; off > 0; off >>= 1) v += __shfl_down(v, off, 64);
    return v;
}

__global__ __launch_bounds__(NT) void mrl_pass1(
    const float* __restrict__ logits,
    const int*   __restrict__ targets,
    const float* __restrict__ counts,
    float*       __restrict__ part,   // [3*NB]: ce | tp | cnt
    int B)
{
    __shared__ float s_bw[C];
    __shared__ float s_red[(NT / 64) * 3];

    if (threadIdx.x == 0) {
        float w[C];
        float ws = 0.0f;
        #pragma unroll
        for (int c = 0; c < C; ++c) { w[c] = rsqrtf(counts[c] + 1.0f); ws += w[c]; }
        const float scale = (float)C / ws;
        #pragma unroll
        for (int c = 0; c < C; ++c) s_bw[c] = w[c] * scale;
    }
    __syncthreads();

    const float inv_temp = 1.0f / 1.5f;
    const float c_uni   = 0.05f / 8.0f;
    const float c_one   = 1.0f - 0.05f;
    const float b_uni   = 0.1f / 8.0f;
    const float b_one   = 1.0f - 0.1f;
    const float b_extra = 0.1f * 0.5f / 3.0f;
    const float b_norm  = 1.0f / (1.0f + 3.0f * (0.1f * 0.5f / 3.0f)); // 1/1.05

    float ce_sum = 0.0f, tp_sum = 0.0f, cnt_sum = 0.0f;

    const int stride = gridDim.x * blockDim.x;
    #pragma unroll 2
    for (int i = blockIdx.x * blockDim.x + threadIdx.x; i < B; i += stride) {
        const float4* row = reinterpret_cast<const float4*>(logits + (size_t)i * 8);
        const float4 a = row[0];
        const float4 b = row[1];
        const float l[8] = {a.x, a.y, a.z, a.w, b.x, b.y, b.z, b.w};
        const int t = targets[i];

        // max + argmax (first-max tie-break, matches jnp.argmax)
        float m = l[0];
        int   p = 0;
        #pragma unroll
        for (int j = 1; j < 8; ++j) { if (l[j] > m) { m = l[j]; p = j; } }

        // temp-1 softmax pieces (cancer prob)
        float se = 0.0f, e0, e1, e3;
        {
            float e[8];
            #pragma unroll
            for (int j = 0; j < 8; ++j) { e[j] = __expf(l[j] - m); se += e[j]; }
            e0 = e[0]; e1 = e[1]; e3 = e[3];
        }
        const float cp = (e0 + e1 + e3) / se;

        // temp-1.5 log-sum-exp
        float se2 = 0.0f;
        #pragma unroll
        for (int j = 0; j < 8; ++j) se2 += __expf((l[j] - m) * inv_temp);
        const float logZ = m * inv_temp + __logf(se2);

        // dot(smoothed_labels, x) without materializing the row
        float S = 0.0f;
        #pragma unroll
        for (int j = 0; j < 8; ++j) S += l[j];
        const float X  = S * inv_temp;
        const float Xc = (l[0] + l[1] + l[3]) * inv_temp;
        float lt = l[0];
        #pragma unroll
        for (int j = 1; j < 8; ++j) lt = (t == j) ? l[j] : lt;
        const float xt = lt * inv_temp;

        const bool isct = ((1u << t) & 0xBu) != 0u;
        const bool iscp = ((1u << p) & 0xBu) != 0u;

        float dot;
        if (isct) dot = c_uni * X + c_one * xt;
        else      dot = (b_uni * X + b_one * xt + b_extra * Xc) * b_norm;

        float ce = (logZ - dot) * s_bw[t];

        float mult = (isct && !iscp) ? 3.0f : 1.0f;
        if (t == 0 && !iscp) mult = 5.0f;
        if (isct && p != t) mult *= 2.0f;
        ce *= mult;

        ce_sum += ce;
        if (isct) { tp_sum += cp; cnt_sum += 1.0f; }
    }

    // block reduction (fixed order -> deterministic)
    float v0 = wave_reduce_sum(ce_sum);
    float v1 = wave_reduce_sum(tp_sum);
    float v2 = wave_reduce_sum(cnt_sum);
    const int lane = threadIdx.x & 63;
    const int wid  = threadIdx.x >> 6;
    if (lane == 0) {
        s_red[wid * 3 + 0] = v0;
        s_red[wid * 3 + 1] = v1;
        s_red[wid * 3 + 2] = v2;
    }
    __syncthreads();
    if (threadIdx.x == 0) {
        float r0 = 0.0f, r1 = 0.0f, r2 = 0.0f;
        #pragma unroll
        for (int w = 0; w < NT / 64; ++w) {
            r0 += s_red[w * 3 + 0];
            r1 += s_red[w * 3 + 1];
            r2 += s_red[w * 3 + 2];
        }
        part[blockIdx.x]          = r0;
        part[NB + blockIdx.x]     = r1;
        part[2 * NB + blockIdx.x] = r2;
    }
}

__global__ __launch_bounds__(NT) void mrl_pass2(
    const float* __restrict__ part,
    float*       __restrict__ out,
    int B)
{
    __shared__ float s_red[(NT / 64) * 3];

    // NB=1024 floats per segment = 256 threads x 1 float4 each
    const float4* p4 = reinterpret_cast<const float4*>(part);
    const int k = threadIdx.x;
    float ce, tp, cnt;
    {
        const float4 a = p4[k];                    // ce segment
        const float4 b = p4[NB / 4 + k];           // tp segment
        const float4 c = p4[2 * (NB / 4) + k];     // cnt segment
        ce  = (a.x + a.y) + (a.z + a.w);
        tp  = (b.x + b.y) + (b.z + b.w);
        cnt = (c.x + c.y) + (c.z + c.w);
    }
    float v0 = wave_reduce_sum(ce);
    float v1 = wave_reduce_sum(tp);
    float v2 = wave_reduce_sum(cnt);
    const int lane = threadIdx.x & 63;
    const int wid  = threadIdx.x >> 6;
    if (lane == 0) {
        s_red[wid * 3 + 0] = v0;
        s_red[wid * 3 + 1] = v1;
        s_red[wid * 3 + 2] = v2;
    }
    __syncthreads();
    if (threadIdx.x == 0) {
        float r0 = 0.0f, r1 = 0.0f, r2 = 0.0f;
        #pragma unroll
        for (int w = 0; w < NT / 64; ++w) {
            r0 += s_red[w * 3 + 0];
            r1 += s_red[w * 3 + 1];
            r2 += s_red[w * 3 + 2];
        }
        const float base_loss   = r0 / (float)B;
        const float recall_loss = 1.0f - r1 / (r2 + 1e-8f);
        out[0] = base_loss + 0.5f * recall_loss;
    }
}

extern "C" void kernel_launch(void* const* d_in, const int* in_sizes, int n_in,
                              void* d_out, int out_size, void* d_ws, size_t ws_size,
                              hipStream_t stream) {
    const float* logits  = (const float*)d_in[0];
    const int*   targets = (const int*)d_in[1];
    const float* counts  = (const float*)d_in[2];
    float* out  = (float*)d_out;
    float* part = (float*)d_ws;   // 3*NB floats = 12 KB scratch
    const int B = in_sizes[1];

    mrl_pass1<<<NB, NT, 0, stream>>>(logits, targets, counts, part, B);
    mrl_pass2<<<1, NT, 0, stream>>>(part, out, B);
}